// Round 8
// baseline (26.474 us; speedup 1.0000x reference)
//
#include <hip/hip_runtime.h>

// DocumentBertScoringLoss: loss = MSE + MR + SIM over B=8192 fp32 vectors.
// MR term == mean over all (m,n) of max(0, 0.1 - |p_m - p_n|) (verified r1).
// Identity:  sum max(0, 0.1-|d|)  =  0.1*B^2 - sum min(|d|, 0.1)   (exact).
//
// Structure history (measured):
//   r1 two-kernel scalar-LDS pairwise: 18.4 us
//   r2 ticket + 4-byte memset node: +39 us (fillBufferAligned). DEAD END.
//   r3 cooperative grid.sync(): 104 us/dispatch. DEAD END.
//   r4 two-kernel, float4-LDS f32, uniform: 15.6 us.
//   r6 triangle + divergent band tiles: 21.7 us. DEAD END (stragglers).
//   r7 two-kernel, packed-f16 min-trick, uniform: 14.8 us (best).
// r8: SINGLE dispatch. r2's ticket finalize, but SELF-RESETTING counter:
//     NBLOCKS=1024 is a power of two, so (ticket & 1023)==1023 selects
//     exactly one block per call from ANY starting value (poison 0xAA ok,
//     u32 wrap ok) -> no memset node needed. Release via __threadfence +
//     atomicAdd; combine reads partials with agent-scope loads (r2-proven).

#define B_N 8192
#define THREADS 256
#define M_PER_THREAD 2
#define MB (THREADS * M_PER_THREAD)   // 512 m-rows per block
#define NXB (B_N / MB)                // 16 m-chunks
#define CHUNK 128                     // n's staged in LDS per block
#define NYB (B_N / CHUNK)             // 64 n-chunks
#define NBLOCKS (NXB * NYB)           // 1024 blocks (power of 2 - required!)

typedef _Float16 h8 __attribute__((ext_vector_type(8)));

__device__ __forceinline__ float block_reduce_sum(float v, float* sbuf) {
    #pragma unroll
    for (int off = 32; off > 0; off >>= 1)
        v += __shfl_down(v, off, 64);
    const int lane = threadIdx.x & 63;
    const int wave = threadIdx.x >> 6;
    if (lane == 0) sbuf[wave] = v;
    __syncthreads();
    if (threadIdx.x == 0) {
        float s = 0.f;
        #pragma unroll
        for (int w = 0; w < THREADS / 64; ++w) s += sbuf[w];
        sbuf[0] = s;
    }
    __syncthreads();
    const float r = sbuf[0];
    __syncthreads();
    return r;
}

__global__ void __launch_bounds__(THREADS)
fused_kernel(const float* __restrict__ p, const float* __restrict__ g,
             float* __restrict__ pairPartial,   // [NBLOCKS]
             float* __restrict__ linPartial,    // [NXB*4]
             unsigned int* __restrict__ counter,
             float* __restrict__ out) {
    __shared__ alignas(16) _Float16 s_h[CHUNK];
    __shared__ float sbuf[THREADS / 64];
    __shared__ int s_last;

    const int tid = threadIdx.x;
    const int bx = blockIdx.x, by = blockIdx.y;
    const int m0 = bx * MB + tid;               // coalesced
    const int m1 = m0 + THREADS;
    const float pm0f = p[m0];
    const float pm1f = p[m1];

    if (tid < CHUNK) s_h[tid] = (_Float16)p[by * CHUNK + tid];
    __syncthreads();

    // Branch-free packed-f16 loop: acc += min(|pm - v|, 0.1) per element.
    const h8* s8 = (const h8*)s_h;
    const _Float16 pm0s = (_Float16)pm0f;
    const _Float16 pm1s = (_Float16)pm1f;
    const h8 pm0 = {pm0s, pm0s, pm0s, pm0s, pm0s, pm0s, pm0s, pm0s};
    const h8 pm1 = {pm1s, pm1s, pm1s, pm1s, pm1s, pm1s, pm1s, pm1s};
    const _Float16 bs = (_Float16)0.1f;
    const h8 bias = {bs, bs, bs, bs, bs, bs, bs, bs};
    h8 acc0 = {0, 0, 0, 0, 0, 0, 0, 0};
    h8 acc1 = {0, 0, 0, 0, 0, 0, 0, 0};
    #pragma unroll
    for (int j = 0; j < CHUNK / 8; ++j) {       // 16 x ds_read_b128 (broadcast)
        const h8 v = s8[j];
        acc0 += __builtin_elementwise_min(__builtin_elementwise_abs(pm0 - v), bias);
        acc1 += __builtin_elementwise_min(__builtin_elementwise_abs(pm1 - v), bias);
    }
    float minsum = 0.f;
    #pragma unroll
    for (int k = 0; k < 8; ++k)
        minsum += (float)acc0[k] + (float)acc1[k];

    const float s = block_reduce_sum(minsum, sbuf);
    if (tid == 0) pairPartial[by * NXB + bx] = s;

    if (by == 0) {                              // linear terms (block-uniform, f32)
        const float gv0 = g[m0], gv1 = g[m1];
        const float d0 = pm0f - gv0, d1 = pm1f - gv1;
        float sq  = d0 * d0 + d1 * d1;
        float dot = pm0f * gv0 + pm1f * gv1;
        float npp = pm0f * pm0f + pm1f * pm1f;
        float ngg = gv0 * gv0 + gv1 * gv1;
        sq  = block_reduce_sum(sq, sbuf);
        dot = block_reduce_sum(dot, sbuf);
        npp = block_reduce_sum(npp, sbuf);
        ngg = block_reduce_sum(ngg, sbuf);
        if (tid == 0) {
            linPartial[bx * 4 + 0] = sq;
            linPartial[bx * 4 + 1] = dot;
            linPartial[bx * 4 + 2] = npp;
            linPartial[bx * 4 + 3] = ngg;
        }
    }

    // Self-resetting ticket: counter is NEVER reset (poison/any start ok).
    // NBLOCKS is a power of two, so exactly one block per call sees
    // (t & (NBLOCKS-1)) == NBLOCKS-1, even across u32 wraparound.
    if (tid == 0) {
        __threadfence();                        // release partial stores
        const unsigned int t = atomicAdd(counter, 1u);
        s_last = ((t & (NBLOCKS - 1)) == (NBLOCKS - 1));
    }
    __syncthreads();
    if (!s_last) return;

    // Last-finishing block combines everything in fixed order -> deterministic.
    float minsum_t = 0.f;
    #pragma unroll
    for (int k = 0; k < NBLOCKS / THREADS; ++k)
        minsum_t += __hip_atomic_load(&pairPartial[k * THREADS + tid],
                                      __ATOMIC_RELAXED, __HIP_MEMORY_SCOPE_AGENT);
    minsum_t = block_reduce_sum(minsum_t, sbuf);

    float lv[4];
    #pragma unroll
    for (int k = 0; k < 4; ++k) {
        float v = 0.f;
        if (tid < NXB)
            v = __hip_atomic_load(&linPartial[tid * 4 + k],
                                  __ATOMIC_RELAXED, __HIP_MEMORY_SCOPE_AGENT);
        lv[k] = block_reduce_sum(v, sbuf);
    }

    if (tid == 0) {
        const float mse = lv[0] / (float)B_N;
        const float mrm = 0.1f - minsum_t / ((float)B_N * (float)B_N);
        const float denom = fmaxf(sqrtf(lv[2]) * sqrtf(lv[3]), 1e-8f);
        const float sim = 1.f - lv[1] / denom;
        out[0] = mse + mrm + sim;               // alpha = beta = gamma = 1
    }
}

extern "C" void kernel_launch(void* const* d_in, const int* in_sizes, int n_in,
                              void* d_out, int out_size, void* d_ws, size_t ws_size,
                              hipStream_t stream) {
    const float* p = (const float*)d_in[0];
    const float* g = (const float*)d_in[1];
    float* pairPartial = (float*)d_ws;            // 1024 floats, rewritten each call
    float* linPartial  = (float*)d_ws + NBLOCKS;  // 64 floats, rewritten each call
    unsigned int* counter = (unsigned int*)((char*)d_ws + 8192);  // never reset

    dim3 grid(NXB, NYB);
    fused_kernel<<<grid, THREADS, 0, stream>>>(p, g, pairPartial, linPartial,
                                               counter, (float*)d_out);
}

// Round 9
// 13.297 us; speedup vs baseline: 1.9910x; 1.9910x over previous
//
#include <hip/hip_runtime.h>

// DocumentBertScoringLoss: loss = MSE + MR + SIM over B=8192 fp32 vectors.
// MR term == mean over all (m,n) of max(0, 0.1 - |p_m - p_n|) (verified r1).
// Identity:  sum max(0, 0.1-|d|)  =  0.1*B^2 - sum min(|d|, 0.1)   (exact).
//
// Structure history (measured):
//   r1 two-kernel scalar-LDS pairwise: 18.4 us
//   r2 ticket + 4-byte memset node: 27.4 us. DEAD END.
//   r3 cooperative grid.sync(): 104 us/dispatch. DEAD END.
//   r4 two-kernel, float4-LDS f32, uniform: 15.6 us.
//   r6 triangle + divergent band tiles: 21.7 us. DEAD END (stragglers).
//   r7 two-kernel, packed-f16 min-trick, uniform: 14.8 us (best).
//   r8 fused ticket, no memset: 26.5 us. DEAD END — per-block device-scope
//      threadfence (L2 writeback) + cross-XCD atomic chain is the cost, and
//      the mask-selected "last" ticket is racy with unaligned poison start.
// r9: keep r7 structure; micro-opt both kernels. Pairwise: 512 blocks
//     (2/CU exact, CHUNK=256). Finalize: float2 partial loads + single
//     wave-shuffle fold for the 4 linear terms (1 block_reduce instead of 5).

#define B_N 8192
#define THREADS 256
#define M_PER_THREAD 2
#define MB (THREADS * M_PER_THREAD)   // 512 m-rows per block
#define NXB (B_N / MB)                // 16 m-chunks
#define CHUNK 256                     // n's staged in LDS per block
#define NYB (B_N / CHUNK)             // 32 n-chunks
#define NBLOCKS (NXB * NYB)           // 512 blocks = 2/CU exactly

typedef _Float16 h8 __attribute__((ext_vector_type(8)));

__device__ __forceinline__ float block_reduce_sum(float v, float* sbuf) {
    #pragma unroll
    for (int off = 32; off > 0; off >>= 1)
        v += __shfl_down(v, off, 64);
    const int lane = threadIdx.x & 63;
    const int wave = threadIdx.x >> 6;
    if (lane == 0) sbuf[wave] = v;
    __syncthreads();
    if (threadIdx.x == 0) {
        float s = 0.f;
        #pragma unroll
        for (int w = 0; w < THREADS / 64; ++w) s += sbuf[w];
        sbuf[0] = s;
    }
    __syncthreads();
    const float r = sbuf[0];
    __syncthreads();
    return r;
}

__global__ void __launch_bounds__(THREADS)
pairwise_kernel(const float* __restrict__ p, const float* __restrict__ g,
                float* __restrict__ pairPartial,   // [NBLOCKS]
                float* __restrict__ linPartial) {  // [NXB*4]
    __shared__ alignas(16) _Float16 s_h[CHUNK];
    __shared__ float sbuf[THREADS / 64];

    const int tid = threadIdx.x;
    const int bx = blockIdx.x, by = blockIdx.y;
    const int m0 = bx * MB + tid;               // coalesced
    const int m1 = m0 + THREADS;
    const float pm0f = p[m0];
    const float pm1f = p[m1];

    s_h[tid] = (_Float16)p[by * CHUNK + tid];   // CHUNK == THREADS
    __syncthreads();

    // Branch-free packed-f16 loop: acc += min(|pm - v|, 0.1) per element.
    // Per h8 per row: 4x v_pk_sub, 2x v_and (abs), 4x v_pk_min, 4x v_pk_add.
    const h8* s8 = (const h8*)s_h;
    const _Float16 pm0s = (_Float16)pm0f;
    const _Float16 pm1s = (_Float16)pm1f;
    const h8 pm0 = {pm0s, pm0s, pm0s, pm0s, pm0s, pm0s, pm0s, pm0s};
    const h8 pm1 = {pm1s, pm1s, pm1s, pm1s, pm1s, pm1s, pm1s, pm1s};
    const _Float16 bs = (_Float16)0.1f;
    const h8 bias = {bs, bs, bs, bs, bs, bs, bs, bs};
    h8 acc0 = {0, 0, 0, 0, 0, 0, 0, 0};
    h8 acc1 = {0, 0, 0, 0, 0, 0, 0, 0};
    #pragma unroll
    for (int j = 0; j < CHUNK / 8; ++j) {       // 32 x ds_read_b128 (broadcast)
        const h8 v = s8[j];
        acc0 += __builtin_elementwise_min(__builtin_elementwise_abs(pm0 - v), bias);
        acc1 += __builtin_elementwise_min(__builtin_elementwise_abs(pm1 - v), bias);
    }
    const h8 a = acc0 + acc1;                   // each lane <= 6.4, f16-safe
    float minsum = 0.f;
    #pragma unroll
    for (int k = 0; k < 8; ++k) minsum += (float)a[k];

    const float s = block_reduce_sum(minsum, sbuf);
    if (tid == 0) pairPartial[by * NXB + bx] = s;

    if (by == 0) {                              // linear terms (block-uniform, f32)
        const float gv0 = g[m0], gv1 = g[m1];
        const float d0 = pm0f - gv0, d1 = pm1f - gv1;
        float sq  = d0 * d0 + d1 * d1;
        float dot = pm0f * gv0 + pm1f * gv1;
        float npp = pm0f * pm0f + pm1f * pm1f;
        float ngg = gv0 * gv0 + gv1 * gv1;
        sq  = block_reduce_sum(sq, sbuf);
        dot = block_reduce_sum(dot, sbuf);
        npp = block_reduce_sum(npp, sbuf);
        ngg = block_reduce_sum(ngg, sbuf);
        if (tid == 0) {
            linPartial[bx * 4 + 0] = sq;
            linPartial[bx * 4 + 1] = dot;
            linPartial[bx * 4 + 2] = npp;
            linPartial[bx * 4 + 3] = ngg;
        }
    }
}

__global__ void __launch_bounds__(THREADS)
finalize_kernel(const float* __restrict__ pairPartial,
                const float* __restrict__ linPartial,
                float* __restrict__ out) {
    __shared__ float sbuf[THREADS / 64];

    // minsum: 512 floats, one float2 per thread, one block reduce.
    const float2* pp2 = (const float2*)pairPartial;
    const float2 v2 = pp2[threadIdx.x];
    float minsum = v2.x + v2.y;
    minsum = block_reduce_sum(minsum, sbuf);    // includes trailing syncthreads

    // Linear terms: 64 floats folded within wave 0 only (no barriers).
    // linPartial[b*4 + k]; fold over b via xor-shuffles at strides 4,8,16,32.
    float lv0 = 0.f, lv1 = 0.f, lv2 = 0.f, lv3 = 0.f;
    if (threadIdx.x < 64) {
        float v = linPartial[threadIdx.x];
        v += __shfl_xor(v, 4,  64);
        v += __shfl_xor(v, 8,  64);
        v += __shfl_xor(v, 16, 64);
        v += __shfl_xor(v, 32, 64);             // lane l now holds sum for k = l&3
        lv0 = __shfl(v, 0, 64);
        lv1 = __shfl(v, 1, 64);
        lv2 = __shfl(v, 2, 64);
        lv3 = __shfl(v, 3, 64);
    }

    if (threadIdx.x == 0) {
        const float mse = lv0 / (float)B_N;
        const float mrm = 0.1f - minsum / ((float)B_N * (float)B_N);
        const float denom = fmaxf(sqrtf(lv2) * sqrtf(lv3), 1e-8f);
        const float sim = 1.f - lv1 / denom;
        out[0] = mse + mrm + sim;               // alpha = beta = gamma = 1
    }
}

extern "C" void kernel_launch(void* const* d_in, const int* in_sizes, int n_in,
                              void* d_out, int out_size, void* d_ws, size_t ws_size,
                              hipStream_t stream) {
    const float* p = (const float*)d_in[0];
    const float* g = (const float*)d_in[1];
    float* pairPartial = (float*)d_ws;            // 512 floats, all rewritten each call
    float* linPartial  = (float*)d_ws + NBLOCKS;  // 64 floats, all rewritten each call

    dim3 grid(NXB, NYB);
    pairwise_kernel<<<grid, THREADS, 0, stream>>>(p, g, pairPartial, linPartial);
    finalize_kernel<<<1, THREADS, 0, stream>>>(pairPartial, linPartial, (float*)d_out);
}